// Round 2
// baseline (541.640 us; speedup 1.0000x reference)
//
#include <hip/hip_runtime.h>

#define A_ANCH 102400
#define BATCH  16
#define N_ANN  32
#define NLDM   196
#define ANNW   200   // 4 box + 196 landmark floats per annotation row

// ws layout:
//   [0,    384)    : double acc[B][3]   (pos_sum, bbox_sum, ldm_sum)
//   [512,  640)    : double negsum[B]   (sum of neg losses strictly above bin0)
//   [1024, 1280)   : int    cnts[B][4]  (npos, nneg, nl, unused)
//   [2048, 2112)   : int    cand_cnt[B]
//   [4096, 20480)  : unsigned hist0[B][256]  (top-byte histogram of neg keys)
//   [32768, ...)   : unsigned keys[B][A]
//   [8 MiB, ...)   : unsigned cand[B][A]

#define OFF_ACC     0
#define OFF_NEGSUM  512
#define OFF_CNTS    1024
#define OFF_CANDCNT 2048
#define OFF_HIST0   4096
#define OFF_KEYS    32768
#define OFF_CAND    (8u * 1024u * 1024u)

__device__ __forceinline__ float key_to_val(unsigned kk) {
    unsigned vb = (kk & 0x80000000u) ? (kk ^ 0x80000000u) : ~kk;
    return __uint_as_float(vb);
}

__global__ __launch_bounds__(256) void k_zero(double* acc, double* negsum,
                                              int* cnts, int* cand_cnt, unsigned* hist0) {
    int t = threadIdx.x;
    for (int i = t; i < BATCH * 256; i += 256) hist0[i] = 0u;
    if (t < BATCH * 3) acc[t] = 0.0;
    if (t < BATCH) negsum[t] = 0.0;
    if (t < BATCH * 4) cnts[t] = 0;
    if (t < BATCH) cand_cnt[t] = 0;
}

__global__ __launch_bounds__(256) void k_main(
    const float* __restrict__ cls,      // B*A*2
    const float* __restrict__ breg,     // B*A*4
    const float* __restrict__ lreg,     // B*A*196
    const float* __restrict__ anchors,  // A*4
    const float* __restrict__ ann,      // B*32*200
    double* __restrict__ acc,
    int* __restrict__ cnts,
    unsigned* __restrict__ keys,
    unsigned* __restrict__ hist0)
{
    const int tid = threadIdx.x;
    const int blocksPer = A_ANCH / 256; // 400
    const int b = blockIdx.x / blocksPer;
    const int a = (blockIdx.x % blocksPer) * 256 + tid;

    __shared__ float4 sbox[N_ANN];
    __shared__ int    svalid[N_ANN];
    __shared__ int    bh[256];
    bh[tid] = 0;
    if (tid < N_ANN) {
        float4 bx = *reinterpret_cast<const float4*>(ann + (size_t)(b * N_ANN + tid) * ANNW);
        sbox[tid] = bx;
        svalid[tid] = bx.x > 0.0f;
    }
    __syncthreads();

    float4 av = *reinterpret_cast<const float4*>(anchors + (size_t)a * 4);
    const float aw = av.z - av.x, ah = av.w - av.y;
    const float areaA = aw * ah;

    float best = -1e30f; int arg = 0;
    #pragma unroll
    for (int j = 0; j < N_ANN; ++j) {
        float4 bx = sbox[j];
        float areaB = (bx.z - bx.x) * (bx.w - bx.y);
        float iw = fminf(av.z, bx.z) - fmaxf(av.x, bx.x);
        float ih = fminf(av.w, bx.w) - fmaxf(av.y, bx.y);
        iw = fmaxf(iw, 0.0f); ih = fmaxf(ih, 0.0f);
        float inter = iw * ih;
        float ua = fmaxf(areaA + areaB - inter, 1e-8f);
        float v = svalid[j] ? (inter / ua) : -1.0f;
        if (v > best) { best = v; arg = j; }
    }
    const bool pos = best >= 0.7f;
    const bool neg = best < 0.4f;

    float2 c = *reinterpret_cast<const float2*>(cls + ((size_t)b * A_ANCH + a) * 2);

    // sortable key for descending float order: larger value -> larger key
    float nv = -c.y;
    unsigned bits = __float_as_uint(nv);
    unsigned key = (bits & 0x80000000u) ? ~bits : (bits ^ 0x80000000u);
    keys[(size_t)b * A_ANCH + a] = neg ? key : 0u;
    if (neg) atomicAdd(&bh[key >> 24], 1);

    unsigned long long bp = __ballot(pos);
    unsigned long long bn = __ballot(neg);
    if ((tid & 63) == 0) {
        if (bp) atomicAdd(&cnts[b * 4 + 0], (int)__popcll(bp));
        if (bn) atomicAdd(&cnts[b * 4 + 1], (int)__popcll(bn));
    }

    if (pos) {
        atomicAdd(&acc[b * 3 + 0], (double)(-c.x));

        const float acx = av.x + 0.5f * aw, acy = av.y + 0.5f * ah;
        float4 gb = sbox[arg];
        float gw = gb.z - gb.x, gh = gb.w - gb.y;
        float gcx = gb.x + 0.5f * gw, gcy = gb.y + 0.5f * gh;
        float tdx = (gcx - acx) / (aw + 1e-14f);
        float tdy = (gcy - acy) / (ah + 1e-14f);
        float tdw = logf(gw / aw);
        float tdh = logf(gh / ah);
        float t0 = tdx / 0.1f, t1 = tdy / 0.1f, t2 = tdw / 0.2f, t3 = tdh / 0.2f;

        float4 rv = *reinterpret_cast<const float4*>(breg + ((size_t)b * A_ANCH + a) * 4);
        float bsum = 0.0f, d;
        d = fabsf(t0 - rv.x); bsum += (d < 1.0f) ? 0.5f * d * d : d - 0.5f;
        d = fabsf(t1 - rv.y); bsum += (d < 1.0f) ? 0.5f * d * d : d - 0.5f;
        d = fabsf(t2 - rv.z); bsum += (d < 1.0f) ? 0.5f * d * d : d - 0.5f;
        d = fabsf(t3 - rv.w); bsum += (d < 1.0f) ? 0.5f * d * d : d - 0.5f;
        atomicAdd(&acc[b * 3 + 1], (double)bsum);

        // landmarks: only if matched GT has nonzero landmark sum
        const float* gl = ann + (size_t)(b * N_ANN + arg) * ANNW + 4; // 16B aligned
        float glsum = 0.0f;
        for (int i = 0; i < NLDM; i += 4) {
            float4 g4 = *reinterpret_cast<const float4*>(gl + i);
            glsum += g4.x + g4.y + g4.z + g4.w;
        }
        if (glsum > 0.0f) {
            atomicAdd(&cnts[b * 4 + 2], 1);
            const float* lr = lreg + ((size_t)b * A_ANCH + a) * NLDM; // 8B aligned
            double wsum = 0.0;
            for (int i = 0; i < NLDM; i += 2) {
                float2 l2 = *reinterpret_cast<const float2*>(lr + i);
                float2 g2 = *reinterpret_cast<const float2*>(gl + i);
                // i even -> x-coord, i+1 -> y-coord
                float ltgt0 = (g2.x - acx) / (aw + 1e-14f) / 0.1f;
                float ltgt1 = (g2.y - acy) / (ah + 1e-14f) / 0.1f;
                float s = (i < 68) ? 1.0f : 3.0f;          // i and i+1 share scale region? 68 is even
                float s1 = ((i + 1) < 68) ? 1.0f : 3.0f;
                float dd0 = fabsf(ltgt0 * s - l2.x * s);
                float dd1 = fabsf(ltgt1 * s1 - g2.y * 0.0f - l2.y * s1); // keep formula shape
                float w0 = (dd0 < 3.0f) ? 3.0f * log1pf(dd0 * 0.5f) : dd0 - 0.25112780437753474f;
                float w1 = (dd1 < 3.0f) ? 3.0f * log1pf(dd1 * 0.5f) : dd1 - 0.25112780437753474f;
                wsum += (double)w0 + (double)w1;
            }
            atomicAdd(&acc[b * 3 + 2], wsum);
        }
    }

    __syncthreads();
    if (bh[tid]) atomicAdd(&hist0[b * 256 + tid], (unsigned)bh[tid]);
}

// Derive bin0 (bin containing the keep-th largest key) and rem (how many to take
// from bin0) from hist0. Returns keep. Executed redundantly per block.
__device__ __forceinline__ int derive_bin0(const unsigned* __restrict__ h0,
                                           const int* __restrict__ cnts, int b,
                                           int tid, unsigned* sh, int* s_bin0, int* s_rem) {
    sh[tid] = h0[b * 256 + tid];
    __syncthreads();
    if (tid == 0) {
        int npos = cnts[b * 4 + 0], nneg = cnts[b * 4 + 1];
        int keep = min(nneg, 3 * npos);
        int bin0 = -1, rem = 0;
        if (keep > 0) {
            unsigned cum = 0;
            for (int i = 255; i >= 0; --i) {
                unsigned cc = sh[i];
                if (cum + cc >= (unsigned)keep) { bin0 = i; rem = keep - (int)cum; break; }
                cum += cc;
            }
        }
        s_bin0[0] = bin0; s_rem[0] = rem; s_rem[1] = keep;
    }
    __syncthreads();
    return s_rem[1];
}

__global__ __launch_bounds__(256) void k_pass1(
    const unsigned* __restrict__ keys,
    const unsigned* __restrict__ hist0,
    const int* __restrict__ cnts,
    double* __restrict__ negsum,
    int* __restrict__ cand_cnt,
    unsigned* __restrict__ cand)
{
    const int tid = threadIdx.x;
    const int b = blockIdx.x >> 4;       // 16 chunks per sample
    const int chunk = blockIdx.x & 15;
    const int CHUNK = A_ANCH / 16;       // 6400

    __shared__ unsigned sh[256];
    __shared__ int s_bin0[1];
    __shared__ int s_rem[2];
    int keep = derive_bin0(hist0, cnts, b, tid, sh, s_bin0, s_rem);
    if (keep <= 0) return;
    const unsigned bin0 = (unsigned)s_bin0[0];

    const unsigned* k = keys + (size_t)b * A_ANCH + (size_t)chunk * CHUNK;
    double lsum = 0.0;
    const int lane = tid & 63;
    for (int i = tid; i < CHUNK; i += 256) {
        unsigned kk = k[i];
        unsigned top = kk >> 24;
        if (top > bin0) lsum += (double)key_to_val(kk);
        bool match = (top == bin0);
        unsigned long long m = __ballot(match);
        if (m) {
            int leader = __ffsll((long long)m) - 1;
            int base = 0;
            if (lane == leader) base = atomicAdd(&cand_cnt[b], (int)__popcll(m));
            base = __shfl(base, leader);
            if (match) {
                int rank = (int)__popcll(m & ((1ull << lane) - 1ull));
                cand[(size_t)b * A_ANCH + base + rank] = kk;
            }
        }
    }
    #pragma unroll
    for (int off = 32; off > 0; off >>= 1) lsum += __shfl_down(lsum, off);
    __shared__ double sred[4];
    if (lane == 0) sred[tid >> 6] = lsum;
    __syncthreads();
    if (tid == 0) {
        double t = sred[0] + sred[1] + sred[2] + sred[3];
        if (t != 0.0) atomicAdd(&negsum[b], t);
    }
}

__global__ __launch_bounds__(256) void k_final(
    const float* __restrict__ ann,
    const double* __restrict__ acc,
    const int* __restrict__ cnts,
    const unsigned* __restrict__ hist0,
    const double* __restrict__ negsum,
    const int* __restrict__ cand_cnt,
    const unsigned* __restrict__ cand,
    float* __restrict__ out)
{
    const int b = blockIdx.x;
    const int tid = threadIdx.x;

    __shared__ unsigned sh[256];
    __shared__ int s_bin0[1];
    __shared__ int s_rem[2];
    __shared__ int s_hasgt;
    __shared__ unsigned s_prefix;
    __shared__ int s_r;
    __shared__ double sred[4];

    if (tid < 64) {
        bool v = (tid < N_ANN) && (ann[(size_t)(b * N_ANN + tid) * ANNW] > 0.0f);
        unsigned long long bm = __ballot(v);
        if (tid == 0) s_hasgt = (bm != 0ull) ? 1 : 0;
    }
    int keep = derive_bin0(hist0, cnts, b, tid, sh, s_bin0, s_rem);
    const int npos = cnts[b * 4 + 0];
    const int nl   = cnts[b * 4 + 2];
    const int hasgt = s_hasgt;
    const int c = cand_cnt[b];

    double total = 0.0;
    if (keep > 0 && s_bin0[0] >= 0) {
        unsigned prefix = ((unsigned)s_bin0[0]) << 24;
        int rem = s_rem[0];
        const unsigned* cd = cand + (size_t)b * A_ANCH;

        for (int pass = 1; pass < 4; ++pass) {
            const int shift = 24 - 8 * pass;
            const unsigned maskAbove = 0xFFFFFFFFu << (shift + 8);
            __syncthreads();
            sh[tid] = 0;
            __syncthreads();
            for (int i = tid; i < c; i += 256) {
                unsigned kk = cd[i];
                if ((kk & maskAbove) == prefix)
                    atomicAdd(&sh[(kk >> shift) & 0xFFu], 1u);
            }
            __syncthreads();
            if (tid == 0) {
                unsigned cum = 0;
                for (int bin = 255; bin >= 0; --bin) {
                    unsigned cc = sh[bin];
                    if (cum + cc >= (unsigned)rem) {
                        s_r = rem - (int)cum;
                        s_prefix = prefix | ((unsigned)bin << shift);
                        break;
                    }
                    cum += cc;
                }
            }
            __syncthreads();
            prefix = s_prefix; rem = s_r;
        }
        const unsigned T = prefix;

        double lsum = 0.0;
        for (int i = tid; i < c; i += 256) {
            unsigned kk = cd[i];
            if (kk > T) lsum += (double)key_to_val(kk);
        }
        #pragma unroll
        for (int off = 32; off > 0; off >>= 1) lsum += __shfl_down(lsum, off);
        if ((tid & 63) == 0) sred[tid >> 6] = lsum;
        __syncthreads();
        if (tid == 0) {
            double cs = sred[0] + sred[1] + sred[2] + sred[3];
            total = negsum[b] + cs + (double)rem * (double)key_to_val(T);
        }
    }

    if (tid == 0) {
        double cls_l = 0.0, bbox_l = 0.0, ldm_l = 0.0;
        if (hasgt && npos > 0) {
            double neg_mean = (keep > 0) ? total / (double)keep : 0.0;
            cls_l = acc[b * 3 + 0] / (double)npos + neg_mean;
            bbox_l = acc[b * 3 + 1] / ((double)npos * 4.0);
        }
        if (hasgt && nl > 0) {
            ldm_l = acc[b * 3 + 2] / ((double)nl * 196.0);
        }
        out[b]             = (float)cls_l;
        out[BATCH + b]     = (float)bbox_l;
        out[2 * BATCH + b] = (float)ldm_l;
    }
}

extern "C" void kernel_launch(void* const* d_in, const int* in_sizes, int n_in,
                              void* d_out, int out_size, void* d_ws, size_t ws_size,
                              hipStream_t stream) {
    const float* cls     = (const float*)d_in[0];
    const float* breg    = (const float*)d_in[1];
    const float* lreg    = (const float*)d_in[2];
    const float* anchors = (const float*)d_in[3];
    const float* ann     = (const float*)d_in[4];

    char* ws = (char*)d_ws;
    double*   acc      = (double*)(ws + OFF_ACC);
    double*   negsum   = (double*)(ws + OFF_NEGSUM);
    int*      cnts     = (int*)(ws + OFF_CNTS);
    int*      cand_cnt = (int*)(ws + OFF_CANDCNT);
    unsigned* hist0    = (unsigned*)(ws + OFF_HIST0);
    unsigned* keys     = (unsigned*)(ws + OFF_KEYS);
    unsigned* cand     = (unsigned*)(ws + OFF_CAND);
    float*    out      = (float*)d_out;

    hipLaunchKernelGGL(k_zero, dim3(1), dim3(256), 0, stream,
                       acc, negsum, cnts, cand_cnt, hist0);
    hipLaunchKernelGGL(k_main, dim3(BATCH * (A_ANCH / 256)), dim3(256), 0, stream,
                       cls, breg, lreg, anchors, ann, acc, cnts, keys, hist0);
    hipLaunchKernelGGL(k_pass1, dim3(BATCH * 16), dim3(256), 0, stream,
                       keys, hist0, cnts, negsum, cand_cnt, cand);
    hipLaunchKernelGGL(k_final, dim3(BATCH), dim3(256), 0, stream,
                       ann, acc, cnts, hist0, negsum, cand_cnt, cand, out);
}

// Round 3
// 176.827 us; speedup vs baseline: 3.0631x; 3.0631x over previous
//
#include <hip/hip_runtime.h>

#define A_ANCH 102400
#define BATCH  16
#define N_ANN  32
#define NLDM   196
#define ANNW   200   // 4 box + 196 landmark floats per annotation row
#define BLOCKS_PER 400  // A_ANCH / 256
#define NSLOT  32

// ws layout (bytes):
//  OFF_ACC     0        : double acc[B][3]          (pos_sum, bbox_sum, ldm_sum)
//  OFF_NEGSUM  512      : double negsum[B][16]      (per-chunk, plain stores)
//  OFF_CANDCNT 4096     : int    cand_cnt[B*32]     (padded: one line per sample)
//  OFF_META    8192     : int    meta[B][8]         (npos,nneg,nl,keep,bin0,rem,hasgt,pad)
//  OFF_PCNT    16384    : int4   pcnt[B][400]       (per-block npos,nneg,nl)
//  OFF_HSLOT   131072   : uint   histS[B][32][256]  (replicated top-byte histograms)
//  OFF_KEYS    1 MiB    : uint   keys[B][A]
//  OFF_CAND    8 MiB    : uint   cand[B][A]

#define OFF_ACC     0
#define OFF_NEGSUM  512
#define OFF_CANDCNT 4096
#define OFF_META    8192
#define OFF_PCNT    16384
#define OFF_HSLOT   131072
#define OFF_KEYS    (1u << 20)
#define OFF_CAND    (8u << 20)

__device__ __forceinline__ float key_to_val(unsigned kk) {
    unsigned vb = (kk & 0x80000000u) ? (kk ^ 0x80000000u) : ~kk;
    return __uint_as_float(vb);
}

__global__ __launch_bounds__(256) void k_zero(double* acc, double* negsum,
                                              int* cand_cnt, unsigned* histS) {
    int t = blockIdx.x * 256 + threadIdx.x;
    int nt = gridDim.x * 256;
    for (int i = t; i < BATCH * NSLOT * 256; i += nt) histS[i] = 0u;
    for (int i = t; i < BATCH * 3; i += nt) acc[i] = 0.0;
    for (int i = t; i < BATCH * 16; i += nt) negsum[i] = 0.0;
    for (int i = t; i < BATCH * 32; i += nt) cand_cnt[i] = 0;
}

__global__ __launch_bounds__(256) void k_main(
    const float* __restrict__ cls,      // B*A*2
    const float* __restrict__ breg,     // B*A*4
    const float* __restrict__ lreg,     // B*A*196
    const float* __restrict__ anchors,  // A*4
    const float* __restrict__ ann,      // B*32*200
    double* __restrict__ acc,
    int4* __restrict__ pcnt,
    unsigned* __restrict__ keys,
    unsigned* __restrict__ histS)
{
    const int tid = threadIdx.x;
    const int b = blockIdx.x / BLOCKS_PER;
    const int blk = blockIdx.x % BLOCKS_PER;
    const int a = blk * 256 + tid;

    __shared__ float4 sbox[N_ANN];
    __shared__ int    svalid[N_ANN];
    __shared__ int    bh[256];
    __shared__ int    s_cnt[4][3];
    __shared__ double s_sum[4][3];
    bh[tid] = 0;
    if (tid < N_ANN) {
        float4 bx = *reinterpret_cast<const float4*>(ann + (size_t)(b * N_ANN + tid) * ANNW);
        sbox[tid] = bx;
        svalid[tid] = bx.x > 0.0f;
    }
    __syncthreads();

    float4 av = *reinterpret_cast<const float4*>(anchors + (size_t)a * 4);
    const float aw = av.z - av.x, ah = av.w - av.y;
    const float areaA = aw * ah;

    float best = -1e30f; int arg = 0;
    #pragma unroll
    for (int j = 0; j < N_ANN; ++j) {
        float4 bx = sbox[j];
        float areaB = (bx.z - bx.x) * (bx.w - bx.y);
        float iw = fminf(av.z, bx.z) - fmaxf(av.x, bx.x);
        float ih = fminf(av.w, bx.w) - fmaxf(av.y, bx.y);
        iw = fmaxf(iw, 0.0f); ih = fmaxf(ih, 0.0f);
        float inter = iw * ih;
        float ua = fmaxf(areaA + areaB - inter, 1e-8f);
        float v = svalid[j] ? (inter / ua) : -1.0f;
        if (v > best) { best = v; arg = j; }
    }
    const bool pos = best >= 0.7f;
    const bool neg = best < 0.4f;

    float2 c = *reinterpret_cast<const float2*>(cls + ((size_t)b * A_ANCH + a) * 2);

    // sortable key for descending float order: larger value -> larger key
    float nv = -c.y;
    unsigned bits = __float_as_uint(nv);
    unsigned key = (bits & 0x80000000u) ? ~bits : (bits ^ 0x80000000u);
    keys[(size_t)b * A_ANCH + a] = neg ? key : 0u;
    if (neg) atomicAdd(&bh[key >> 24], 1);

    double v_pos = 0.0, v_bb = 0.0, v_ldm = 0.0;
    float glsum = 0.0f;
    const float acx = av.x + 0.5f * aw, acy = av.y + 0.5f * ah;

    if (pos) {
        v_pos = (double)(-c.x);

        float4 gb = sbox[arg];
        float gw = gb.z - gb.x, gh = gb.w - gb.y;
        float gcx = gb.x + 0.5f * gw, gcy = gb.y + 0.5f * gh;
        float t0 = ((gcx - acx) / (aw + 1e-14f)) / 0.1f;
        float t1 = ((gcy - acy) / (ah + 1e-14f)) / 0.1f;
        float t2 = logf(gw / aw) / 0.2f;
        float t3 = logf(gh / ah) / 0.2f;

        float4 rv = *reinterpret_cast<const float4*>(breg + ((size_t)b * A_ANCH + a) * 4);
        float bsum = 0.0f, d;
        d = fabsf(t0 - rv.x); bsum += (d < 1.0f) ? 0.5f * d * d : d - 0.5f;
        d = fabsf(t1 - rv.y); bsum += (d < 1.0f) ? 0.5f * d * d : d - 0.5f;
        d = fabsf(t2 - rv.z); bsum += (d < 1.0f) ? 0.5f * d * d : d - 0.5f;
        d = fabsf(t3 - rv.w); bsum += (d < 1.0f) ? 0.5f * d * d : d - 0.5f;
        v_bb = (double)bsum;

        const float* gl = ann + (size_t)(b * N_ANN + arg) * ANNW + 4; // 16B aligned
        for (int i = 0; i < NLDM; i += 4) {
            float4 g4 = *reinterpret_cast<const float4*>(gl + i);
            glsum += g4.x + g4.y + g4.z + g4.w;
        }
    }
    const bool lpos = pos && (glsum > 0.0f);
    if (lpos) {
        const float* gl = ann + (size_t)(b * N_ANN + arg) * ANNW + 4;
        const float* lr = lreg + ((size_t)b * A_ANCH + a) * NLDM; // 784B stride: 16B aligned
        const float inv_aw = 1.0f / ((aw + 1e-14f) * 0.1f);
        const float inv_ah = 1.0f / ((ah + 1e-14f) * 0.1f);
        double wsum = 0.0;
        for (int i = 0; i < NLDM; i += 4) {
            float4 l4 = *reinterpret_cast<const float4*>(lr + i);
            float4 g4 = *reinterpret_cast<const float4*>(gl + i);
            float s = (i < 68) ? 1.0f : 3.0f;  // 68 % 4 == 0: no straddle
            float lt0 = (g4.x - acx) * inv_aw;
            float lt1 = (g4.y - acy) * inv_ah;
            float lt2 = (g4.z - acx) * inv_aw;
            float lt3 = (g4.w - acy) * inv_ah;
            float d0 = fabsf(lt0 * s - l4.x * s);
            float d1 = fabsf(lt1 * s - l4.y * s);
            float d2 = fabsf(lt2 * s - l4.z * s);
            float d3 = fabsf(lt3 * s - l4.w * s);
            float w0 = (d0 < 3.0f) ? 3.0f * log1pf(d0 * 0.5f) : d0 - 0.25112780437753474f;
            float w1 = (d1 < 3.0f) ? 3.0f * log1pf(d1 * 0.5f) : d1 - 0.25112780437753474f;
            float w2 = (d2 < 3.0f) ? 3.0f * log1pf(d2 * 0.5f) : d2 - 0.25112780437753474f;
            float w3 = (d3 < 3.0f) ? 3.0f * log1pf(d3 * 0.5f) : d3 - 0.25112780437753474f;
            wsum += (double)w0 + (double)w1 + (double)w2 + (double)w3;
        }
        v_ldm = wsum;
    }

    // --- block-level reduction: counts (no atomics) + pos sums (rare atomics) ---
    unsigned long long bp = __ballot(pos);
    unsigned long long bn = __ballot(neg);
    unsigned long long bl = __ballot(lpos);
    const int wave = tid >> 6, lane = tid & 63;
    if (lane == 0) {
        s_cnt[wave][0] = (int)__popcll(bp);
        s_cnt[wave][1] = (int)__popcll(bn);
        s_cnt[wave][2] = (int)__popcll(bl);
    }
    if (bp) {  // wave-uniform: only waves containing positives pay the shuffle cost
        #pragma unroll
        for (int off = 32; off > 0; off >>= 1) {
            v_pos += __shfl_down(v_pos, off);
            v_bb  += __shfl_down(v_bb, off);
            v_ldm += __shfl_down(v_ldm, off);
        }
    }
    if (lane == 0) {
        s_sum[wave][0] = v_pos;
        s_sum[wave][1] = v_bb;
        s_sum[wave][2] = v_ldm;
    }
    __syncthreads();
    if (tid == 0) {
        int np = s_cnt[0][0] + s_cnt[1][0] + s_cnt[2][0] + s_cnt[3][0];
        int nn = s_cnt[0][1] + s_cnt[1][1] + s_cnt[2][1] + s_cnt[3][1];
        int nl = s_cnt[0][2] + s_cnt[1][2] + s_cnt[2][2] + s_cnt[3][2];
        pcnt[b * BLOCKS_PER + blk] = make_int4(np, nn, nl, 0);
        if (np > 0) {
            atomicAdd(&acc[b * 3 + 0], s_sum[0][0] + s_sum[1][0] + s_sum[2][0] + s_sum[3][0]);
            atomicAdd(&acc[b * 3 + 1], s_sum[0][1] + s_sum[1][1] + s_sum[2][1] + s_sum[3][1]);
            atomicAdd(&acc[b * 3 + 2], s_sum[0][2] + s_sum[1][2] + s_sum[2][2] + s_sum[3][2]);
        }
    }
    // merge block histogram into one of NSLOT replicated per-sample histograms
    if (bh[tid]) {
        unsigned slot = (unsigned)(blockIdx.x & (NSLOT - 1));
        atomicAdd(&histS[((unsigned)b * NSLOT + slot) * 256u + (unsigned)tid],
                  (unsigned)bh[tid]);
    }
}

__global__ __launch_bounds__(256) void k_derive(
    const float* __restrict__ ann,
    const int4* __restrict__ pcnt,
    const unsigned* __restrict__ histS,
    int* __restrict__ meta)
{
    const int b = blockIdx.x;
    const int tid = threadIdx.x;

    __shared__ unsigned shist[256];
    __shared__ int s_c[4][3];
    __shared__ int s_hasgt;

    // fold NSLOT replicated histograms
    unsigned hsum = 0;
    #pragma unroll
    for (int s = 0; s < NSLOT; ++s)
        hsum += histS[((unsigned)b * NSLOT + s) * 256u + tid];
    shist[tid] = hsum;

    // fold per-block counts
    int np = 0, nn = 0, nl = 0;
    for (int i = tid; i < BLOCKS_PER; i += 256) {
        int4 p = pcnt[b * BLOCKS_PER + i];
        np += p.x; nn += p.y; nl += p.z;
    }
    #pragma unroll
    for (int off = 32; off > 0; off >>= 1) {
        np += __shfl_down(np, off);
        nn += __shfl_down(nn, off);
        nl += __shfl_down(nl, off);
    }
    const int wave = tid >> 6, lane = tid & 63;
    if (lane == 0) { s_c[wave][0] = np; s_c[wave][1] = nn; s_c[wave][2] = nl; }

    // hasgt
    bool v = (tid < N_ANN) && (ann[(size_t)(b * N_ANN + tid) * ANNW] > 0.0f);
    unsigned long long bm = __ballot(v);
    if (tid == 0) s_hasgt = (bm != 0ull) ? 1 : 0;
    __syncthreads();

    if (tid == 0) {
        int tnp = s_c[0][0] + s_c[1][0] + s_c[2][0] + s_c[3][0];
        int tnn = s_c[0][1] + s_c[1][1] + s_c[2][1] + s_c[3][1];
        int tnl = s_c[0][2] + s_c[1][2] + s_c[2][2] + s_c[3][2];
        int keep = min(tnn, 3 * tnp);
        int bin0 = -1, rem = 0;
        if (keep > 0) {
            unsigned cum = 0;
            for (int i = 255; i >= 0; --i) {
                unsigned cc = shist[i];
                if (cum + cc >= (unsigned)keep) { bin0 = i; rem = keep - (int)cum; break; }
                cum += cc;
            }
        }
        meta[b * 8 + 0] = tnp;
        meta[b * 8 + 1] = tnn;
        meta[b * 8 + 2] = tnl;
        meta[b * 8 + 3] = keep;
        meta[b * 8 + 4] = bin0;
        meta[b * 8 + 5] = rem;
        meta[b * 8 + 6] = s_hasgt;
        meta[b * 8 + 7] = 0;
    }
}

__global__ __launch_bounds__(256) void k_pass1(
    const unsigned* __restrict__ keys,
    const int* __restrict__ meta,
    double* __restrict__ negsum,
    int* __restrict__ cand_cnt,
    unsigned* __restrict__ cand)
{
    const int tid = threadIdx.x;
    const int b = blockIdx.x >> 4;
    const int chunk = blockIdx.x & 15;
    const int CHUNK = A_ANCH / 16; // 6400

    const int keep = meta[b * 8 + 3];
    const int bin0i = meta[b * 8 + 4];
    if (keep <= 0 || bin0i < 0) return;  // negsum pre-zeroed by k_zero
    const unsigned bin0 = (unsigned)bin0i;

    const unsigned* k = keys + (size_t)b * A_ANCH + (size_t)chunk * CHUNK;
    double lsum = 0.0;
    const int lane = tid & 63;
    for (int i = tid; i < CHUNK; i += 256) {
        unsigned kk = k[i];
        unsigned top = kk >> 24;
        if (top > bin0) lsum += (double)key_to_val(kk);
        bool match = (top == bin0);
        unsigned long long m = __ballot(match);
        if (m) {
            int leader = __ffsll((long long)m) - 1;
            int base = 0;
            if (lane == leader) base = atomicAdd(&cand_cnt[b * 32], (int)__popcll(m));
            base = __shfl(base, leader);
            if (match) {
                int rank = (int)__popcll(m & ((1ull << lane) - 1ull));
                cand[(size_t)b * A_ANCH + base + rank] = kk;
            }
        }
    }
    #pragma unroll
    for (int off = 32; off > 0; off >>= 1) lsum += __shfl_down(lsum, off);
    __shared__ double sred[4];
    if (lane == 0) sred[tid >> 6] = lsum;
    __syncthreads();
    if (tid == 0)
        negsum[b * 16 + chunk] = sred[0] + sred[1] + sred[2] + sred[3];
}

__global__ __launch_bounds__(256) void k_final(
    const double* __restrict__ acc,
    const int* __restrict__ meta,
    const double* __restrict__ negsum,
    const int* __restrict__ cand_cnt,
    const unsigned* __restrict__ cand,
    float* __restrict__ out)
{
    const int b = blockIdx.x;
    const int tid = threadIdx.x;

    __shared__ unsigned sh[256];
    __shared__ unsigned s_prefix;
    __shared__ int s_r;
    __shared__ double sred[4];

    const int npos  = meta[b * 8 + 0];
    const int nl    = meta[b * 8 + 2];
    const int keep  = meta[b * 8 + 3];
    const int bin0i = meta[b * 8 + 4];
    const int rem0  = meta[b * 8 + 5];
    const int hasgt = meta[b * 8 + 6];
    const int c = cand_cnt[b * 32];

    double total = 0.0;
    if (keep > 0 && bin0i >= 0) {
        unsigned prefix = ((unsigned)bin0i) << 24;
        int rem = rem0;
        const unsigned* cd = cand + (size_t)b * A_ANCH;

        for (int pass = 1; pass < 4; ++pass) {
            const int shift = 24 - 8 * pass;
            const unsigned maskAbove = 0xFFFFFFFFu << (shift + 8);
            __syncthreads();
            sh[tid] = 0;
            __syncthreads();
            for (int i = tid; i < c; i += 256) {
                unsigned kk = cd[i];
                if ((kk & maskAbove) == prefix)
                    atomicAdd(&sh[(kk >> shift) & 0xFFu], 1u);
            }
            __syncthreads();
            if (tid == 0) {
                unsigned cum = 0;
                for (int bin = 255; bin >= 0; --bin) {
                    unsigned cc = sh[bin];
                    if (cum + cc >= (unsigned)rem) {
                        s_r = rem - (int)cum;
                        s_prefix = prefix | ((unsigned)bin << shift);
                        break;
                    }
                    cum += cc;
                }
            }
            __syncthreads();
            prefix = s_prefix; rem = s_r;
        }
        const unsigned T = prefix;

        double lsum = 0.0;
        for (int i = tid; i < c; i += 256) {
            unsigned kk = cd[i];
            if (kk > T) lsum += (double)key_to_val(kk);
        }
        #pragma unroll
        for (int off = 32; off > 0; off >>= 1) lsum += __shfl_down(lsum, off);
        if ((tid & 63) == 0) sred[tid >> 6] = lsum;
        __syncthreads();
        if (tid == 0) {
            double ns = 0.0;
            for (int i = 0; i < 16; ++i) ns += negsum[b * 16 + i];
            total = ns + sred[0] + sred[1] + sred[2] + sred[3]
                  + (double)rem * (double)key_to_val(T);
        }
    }

    if (tid == 0) {
        double cls_l = 0.0, bbox_l = 0.0, ldm_l = 0.0;
        if (hasgt && npos > 0) {
            double neg_mean = (keep > 0) ? total / (double)keep : 0.0;
            cls_l = acc[b * 3 + 0] / (double)npos + neg_mean;
            bbox_l = acc[b * 3 + 1] / ((double)npos * 4.0);
        }
        if (hasgt && nl > 0) {
            ldm_l = acc[b * 3 + 2] / ((double)nl * 196.0);
        }
        out[b]             = (float)cls_l;
        out[BATCH + b]     = (float)bbox_l;
        out[2 * BATCH + b] = (float)ldm_l;
    }
}

extern "C" void kernel_launch(void* const* d_in, const int* in_sizes, int n_in,
                              void* d_out, int out_size, void* d_ws, size_t ws_size,
                              hipStream_t stream) {
    const float* cls     = (const float*)d_in[0];
    const float* breg    = (const float*)d_in[1];
    const float* lreg    = (const float*)d_in[2];
    const float* anchors = (const float*)d_in[3];
    const float* ann     = (const float*)d_in[4];

    char* ws = (char*)d_ws;
    double*   acc      = (double*)(ws + OFF_ACC);
    double*   negsum   = (double*)(ws + OFF_NEGSUM);
    int*      cand_cnt = (int*)(ws + OFF_CANDCNT);
    int*      meta     = (int*)(ws + OFF_META);
    int4*     pcnt     = (int4*)(ws + OFF_PCNT);
    unsigned* histS    = (unsigned*)(ws + OFF_HSLOT);
    unsigned* keys     = (unsigned*)(ws + OFF_KEYS);
    unsigned* cand     = (unsigned*)(ws + OFF_CAND);
    float*    out      = (float*)d_out;

    hipLaunchKernelGGL(k_zero, dim3(64), dim3(256), 0, stream,
                       acc, negsum, cand_cnt, histS);
    hipLaunchKernelGGL(k_main, dim3(BATCH * BLOCKS_PER), dim3(256), 0, stream,
                       cls, breg, lreg, anchors, ann, acc, pcnt, keys, histS);
    hipLaunchKernelGGL(k_derive, dim3(BATCH), dim3(256), 0, stream,
                       ann, pcnt, histS, meta);
    hipLaunchKernelGGL(k_pass1, dim3(BATCH * 16), dim3(256), 0, stream,
                       keys, meta, negsum, cand_cnt, cand);
    hipLaunchKernelGGL(k_final, dim3(BATCH), dim3(256), 0, stream,
                       acc, meta, negsum, cand_cnt, cand, out);
}

// Round 4
// 157.645 us; speedup vs baseline: 3.4358x; 1.1217x over previous
//
#include <hip/hip_runtime.h>

#define A_ANCH 102400
#define BATCH  16
#define N_ANN  32
#define NLDM   196
#define ANNW   200   // 4 box + 196 landmark floats per annotation row
#define BLOCKS_PER 400  // A_ANCH / 256
#define NSLOT  32
#define SEL_T  1024
#define CAP    14336    // LDS candidate cap (56KB); spill to global beyond

// ws layout (bytes):
//  OFF_PCNT   16KB  : int4   pcnt[B*400]        (per-block npos,nneg,nl)   plain stores
//  OFF_PSUM   128KB : double psum[B*400*3]      (per-block pos/bbox/ldm)   plain stores
//  OFF_HSLOT  288KB : uint   histS[B][32][256]  (replicated top-byte hist) memset + atomics
//  OFF_KEYS   1MB   : uint   keys[B][A]                                    plain stores
//  OFF_SPILL  8MB   : uint   spill[B][A]        (candidate overflow)
#define OFF_PCNT   (16u << 10)
#define OFF_PSUM   (131072u)
#define OFF_HSLOT  (294912u)
#define OFF_KEYS   (1u << 20)
#define OFF_SPILL  (8u << 20)

__device__ __forceinline__ float key_to_val(unsigned kk) {
    unsigned vb = (kk & 0x80000000u) ? (kk ^ 0x80000000u) : ~kk;
    return __uint_as_float(vb);
}

__global__ __launch_bounds__(256) void k_main(
    const float* __restrict__ cls,      // B*A*2
    const float* __restrict__ breg,     // B*A*4
    const float* __restrict__ lreg,     // B*A*196
    const float* __restrict__ anchors,  // A*4
    const float* __restrict__ ann,      // B*32*200
    int4* __restrict__ pcnt,
    double* __restrict__ psum,
    unsigned* __restrict__ keys,
    unsigned* __restrict__ histS)
{
    const int tid = threadIdx.x;
    const int b = blockIdx.x / BLOCKS_PER;
    const int blk = blockIdx.x % BLOCKS_PER;
    const int a = blk * 256 + tid;

    __shared__ int    bh[256];
    __shared__ int    s_cnt[4][3];
    __shared__ double s_sum[4][3];
    bh[tid] = 0;
    __syncthreads();

    float4 av = *reinterpret_cast<const float4*>(anchors + (size_t)a * 4);
    const float aw = av.z - av.x, ah = av.w - av.y;
    const float areaA = aw * ah;

    // Division-free IoU argmax. Boxes read via wave-uniform addresses -> s_load.
    // Invalid (shifted) boxes cannot overlap anchors: inter==0 naturally, which
    // matches the reference's -1 sentinel for both max and first-index argmax.
    const float* __restrict__ annb = ann + (size_t)b * N_ANN * ANNW;
    float bnum = -1e30f, bden = 1.0f; int arg = 0;
    #pragma unroll 8
    for (int j = 0; j < N_ANN; ++j) {
        float4 bx = *reinterpret_cast<const float4*>(annb + (size_t)j * ANNW);
        float areaB = (bx.z - bx.x) * (bx.w - bx.y);
        float iw = fminf(av.z, bx.z) - fmaxf(av.x, bx.x);
        float ih = fminf(av.w, bx.w) - fmaxf(av.y, bx.y);
        iw = fmaxf(iw, 0.0f); ih = fmaxf(ih, 0.0f);
        float inter = iw * ih;
        float ua = fmaxf(areaA + areaB - inter, 1e-8f);
        bool upd = inter * bden > bnum * ua;
        bnum = upd ? inter : bnum;
        bden = upd ? ua : bden;
        arg  = upd ? j : arg;
    }
    const bool pos = bnum >= 0.7f * bden;
    const bool neg = bnum <  0.4f * bden;

    float2 c = *reinterpret_cast<const float2*>(cls + ((size_t)b * A_ANCH + a) * 2);

    // sortable key for descending float order
    float nv = -c.y;
    unsigned bits = __float_as_uint(nv);
    unsigned key = (bits & 0x80000000u) ? ~bits : (bits ^ 0x80000000u);
    keys[(size_t)b * A_ANCH + a] = neg ? key : 0u;
    if (neg) atomicAdd(&bh[key >> 24], 1);

    double v_pos = 0.0, v_bb = 0.0, v_ldm = 0.0;
    float glsum = 0.0f;
    const float acx = av.x + 0.5f * aw, acy = av.y + 0.5f * ah;

    if (pos) {
        v_pos = (double)(-c.x);

        float4 gb = *reinterpret_cast<const float4*>(annb + (size_t)arg * ANNW);
        float gw = gb.z - gb.x, gh = gb.w - gb.y;
        float gcx = gb.x + 0.5f * gw, gcy = gb.y + 0.5f * gh;
        float t0 = ((gcx - acx) / (aw + 1e-14f)) / 0.1f;
        float t1 = ((gcy - acy) / (ah + 1e-14f)) / 0.1f;
        float t2 = logf(gw / aw) / 0.2f;
        float t3 = logf(gh / ah) / 0.2f;

        float4 rv = *reinterpret_cast<const float4*>(breg + ((size_t)b * A_ANCH + a) * 4);
        float bsum = 0.0f, d;
        d = fabsf(t0 - rv.x); bsum += (d < 1.0f) ? 0.5f * d * d : d - 0.5f;
        d = fabsf(t1 - rv.y); bsum += (d < 1.0f) ? 0.5f * d * d : d - 0.5f;
        d = fabsf(t2 - rv.z); bsum += (d < 1.0f) ? 0.5f * d * d : d - 0.5f;
        d = fabsf(t3 - rv.w); bsum += (d < 1.0f) ? 0.5f * d * d : d - 0.5f;
        v_bb = (double)bsum;

        const float* gl = annb + (size_t)arg * ANNW + 4; // 16B aligned
        for (int i = 0; i < NLDM; i += 4) {
            float4 g4 = *reinterpret_cast<const float4*>(gl + i);
            glsum += g4.x + g4.y + g4.z + g4.w;
        }
    }
    const bool lpos = pos && (glsum > 0.0f);
    if (lpos) {
        const float* gl = annb + (size_t)arg * ANNW + 4;
        const float* lr = lreg + ((size_t)b * A_ANCH + a) * NLDM; // 784B stride: 16B aligned
        const float inv_aw = 1.0f / ((aw + 1e-14f) * 0.1f);
        const float inv_ah = 1.0f / ((ah + 1e-14f) * 0.1f);
        double wsum = 0.0;
        for (int i = 0; i < NLDM; i += 4) {
            float4 l4 = *reinterpret_cast<const float4*>(lr + i);
            float4 g4 = *reinterpret_cast<const float4*>(gl + i);
            float s = (i < 68) ? 1.0f : 3.0f;  // 68 % 4 == 0: no straddle
            float lt0 = (g4.x - acx) * inv_aw;
            float lt1 = (g4.y - acy) * inv_ah;
            float lt2 = (g4.z - acx) * inv_aw;
            float lt3 = (g4.w - acy) * inv_ah;
            float d0 = fabsf(lt0 * s - l4.x * s);
            float d1 = fabsf(lt1 * s - l4.y * s);
            float d2 = fabsf(lt2 * s - l4.z * s);
            float d3 = fabsf(lt3 * s - l4.w * s);
            float w0 = (d0 < 3.0f) ? 3.0f * log1pf(d0 * 0.5f) : d0 - 0.25112780437753474f;
            float w1 = (d1 < 3.0f) ? 3.0f * log1pf(d1 * 0.5f) : d1 - 0.25112780437753474f;
            float w2 = (d2 < 3.0f) ? 3.0f * log1pf(d2 * 0.5f) : d2 - 0.25112780437753474f;
            float w3 = (d3 < 3.0f) ? 3.0f * log1pf(d3 * 0.5f) : d3 - 0.25112780437753474f;
            wsum += (double)w0 + (double)w1 + (double)w2 + (double)w3;
        }
        v_ldm = wsum;
    }

    // block reduction: counts + sums, all plain-stored per block (no global atomics)
    unsigned long long bp = __ballot(pos);
    unsigned long long bn = __ballot(neg);
    unsigned long long bl = __ballot(lpos);
    const int wave = tid >> 6, lane = tid & 63;
    if (lane == 0) {
        s_cnt[wave][0] = (int)__popcll(bp);
        s_cnt[wave][1] = (int)__popcll(bn);
        s_cnt[wave][2] = (int)__popcll(bl);
    }
    if (bp) {
        #pragma unroll
        for (int off = 32; off > 0; off >>= 1) {
            v_pos += __shfl_down(v_pos, off);
            v_bb  += __shfl_down(v_bb, off);
            v_ldm += __shfl_down(v_ldm, off);
        }
    }
    if (lane == 0) {
        s_sum[wave][0] = v_pos;
        s_sum[wave][1] = v_bb;
        s_sum[wave][2] = v_ldm;
    }
    __syncthreads();
    if (tid == 0) {
        int np = s_cnt[0][0] + s_cnt[1][0] + s_cnt[2][0] + s_cnt[3][0];
        int nn = s_cnt[0][1] + s_cnt[1][1] + s_cnt[2][1] + s_cnt[3][1];
        int nl = s_cnt[0][2] + s_cnt[1][2] + s_cnt[2][2] + s_cnt[3][2];
        pcnt[b * BLOCKS_PER + blk] = make_int4(np, nn, nl, 0);
        size_t pbase = (size_t)(b * BLOCKS_PER + blk) * 3;
        psum[pbase + 0] = s_sum[0][0] + s_sum[1][0] + s_sum[2][0] + s_sum[3][0];
        psum[pbase + 1] = s_sum[0][1] + s_sum[1][1] + s_sum[2][1] + s_sum[3][1];
        psum[pbase + 2] = s_sum[0][2] + s_sum[1][2] + s_sum[2][2] + s_sum[3][2];
    }
    if (bh[tid]) {
        unsigned slot = (unsigned)(blockIdx.x & (NSLOT - 1));
        atomicAdd(&histS[((unsigned)b * NSLOT + slot) * 256u + (unsigned)tid],
                  (unsigned)bh[tid]);
    }
}

__global__ __launch_bounds__(SEL_T) void k_sel(
    const float* __restrict__ ann,
    const int4* __restrict__ pcnt,
    const double* __restrict__ psum,
    const unsigned* __restrict__ histS,
    const unsigned* __restrict__ keys,
    unsigned* __restrict__ spill,
    float* __restrict__ out)
{
    const int b = blockIdx.x;
    const int tid = threadIdx.x;
    const int wave = tid >> 6, lane = tid & 63;

    __shared__ unsigned shist[256];
    __shared__ unsigned s_cand[CAP];
    __shared__ int    sredi[16][3];
    __shared__ double sredd[16][3];
    __shared__ int    s_i[8];   // npos,nneg,nl,keep,bin0,rem,hasgt,cnt
    __shared__ double s_d[4];   // acc0,acc1,acc2,negsum
    __shared__ unsigned s_prefix;
    __shared__ int s_r;
    __shared__ int s_cc;

    // 1. fold replicated histograms
    if (tid < 256) {
        unsigned h = 0;
        #pragma unroll
        for (int s = 0; s < NSLOT; ++s)
            h += histS[((unsigned)b * NSLOT + s) * 256u + (unsigned)tid];
        shist[tid] = h;
    }

    // 2. fold per-block counts and sums
    int np = 0, nn = 0, nl = 0;
    double a0 = 0.0, a1 = 0.0, a2 = 0.0;
    for (int i = tid; i < BLOCKS_PER; i += SEL_T) {
        int4 p = pcnt[b * BLOCKS_PER + i];
        np += p.x; nn += p.y; nl += p.z;
        size_t pbase = (size_t)(b * BLOCKS_PER + i) * 3;
        a0 += psum[pbase + 0]; a1 += psum[pbase + 1]; a2 += psum[pbase + 2];
    }
    #pragma unroll
    for (int off = 32; off > 0; off >>= 1) {
        np += __shfl_down(np, off); nn += __shfl_down(nn, off); nl += __shfl_down(nl, off);
        a0 += __shfl_down(a0, off); a1 += __shfl_down(a1, off); a2 += __shfl_down(a2, off);
    }
    if (lane == 0) {
        sredi[wave][0] = np; sredi[wave][1] = nn; sredi[wave][2] = nl;
        sredd[wave][0] = a0; sredd[wave][1] = a1; sredd[wave][2] = a2;
    }

    // 3. hasgt (wave 0)
    if (tid < 64) {
        bool v = (tid < N_ANN) && (ann[(size_t)(b * N_ANN + tid) * ANNW] > 0.0f);
        unsigned long long bm = __ballot(v);
        if (tid == 0) s_i[6] = (bm != 0ull) ? 1 : 0;
    }
    __syncthreads();

    // 4. totals + derive bin0/rem
    if (tid == 0) {
        int tnp = 0, tnn = 0, tnl = 0; double t0 = 0, t1 = 0, t2 = 0;
        for (int w = 0; w < 16; ++w) {
            tnp += sredi[w][0]; tnn += sredi[w][1]; tnl += sredi[w][2];
            t0 += sredd[w][0]; t1 += sredd[w][1]; t2 += sredd[w][2];
        }
        int keep = min(tnn, 3 * tnp);
        int bin0 = -1, rem = 0;
        if (keep > 0) {
            unsigned cum = 0;
            for (int i = 255; i >= 0; --i) {
                unsigned cc = shist[i];
                if (cum + cc >= (unsigned)keep) { bin0 = i; rem = keep - (int)cum; break; }
                cum += cc;
            }
        }
        s_i[0] = tnp; s_i[1] = tnn; s_i[2] = tnl;
        s_i[3] = keep; s_i[4] = bin0; s_i[5] = rem;
        s_d[0] = t0; s_d[1] = t1; s_d[2] = t2;
        s_cc = 0;
    }
    __syncthreads();

    const int keep = s_i[3];
    const int bin0 = s_i[4];
    unsigned* sp = spill + (size_t)b * A_ANCH;

    // 5. scan keys: negsum above bin0, compact bin0 matches
    double lneg = 0.0;
    if (keep > 0) {
        const uint4* k4 = reinterpret_cast<const uint4*>(keys + (size_t)b * A_ANCH);
        const unsigned long long lmask = (1ull << lane) - 1ull;
        for (int i = tid; i < A_ANCH / 4; i += SEL_T) {
            uint4 kv = k4[i];
            #pragma unroll
            for (int e = 0; e < 4; ++e) {
                unsigned kk = (e == 0) ? kv.x : (e == 1) ? kv.y : (e == 2) ? kv.z : kv.w;
                int top = (int)(kk >> 24);
                if (top > bin0) lneg += (double)key_to_val(kk);
                bool m = (top == bin0);
                unsigned long long bm = __ballot(m);
                if (bm) {
                    int ldr = __ffsll((long long)bm) - 1;
                    int base = 0;
                    if (lane == ldr) base = atomicAdd(&s_cc, (int)__popcll(bm));
                    base = __shfl(base, ldr);
                    if (m) {
                        int idx = base + (int)__popcll(bm & lmask);
                        if (idx < CAP) s_cand[idx] = kk;
                        else sp[idx - CAP] = kk;
                    }
                }
            }
        }
    }
    #pragma unroll
    for (int off = 32; off > 0; off >>= 1) lneg += __shfl_down(lneg, off);
    __syncthreads();               // sredd reuse + s_cc final
    if (lane == 0) sredd[wave][0] = lneg;
    __syncthreads();
    if (tid == 0) {
        double t = 0.0;
        for (int w = 0; w < 16; ++w) t += sredd[w][0];
        s_d[3] = t;
        s_i[7] = s_cc;
    }
    __syncthreads();
    const int cnt = s_i[7];

    // 6. radix passes 1..3 over candidates
    unsigned prefix = ((unsigned)bin0) << 24;
    for (int pass = 1; pass < 4; ++pass) {
        const int shift = 24 - 8 * pass;
        const unsigned maskAbove = 0xFFFFFFFFu << (shift + 8);
        if (tid < 256) shist[tid] = 0;
        __syncthreads();
        for (int i = tid; i < cnt; i += SEL_T) {
            unsigned kk = (i < CAP) ? s_cand[i] : sp[i - CAP];
            if ((kk & maskAbove) == prefix)
                atomicAdd(&shist[(kk >> shift) & 0xFFu], 1u);
        }
        __syncthreads();
        if (tid == 0) {
            int rem = (pass == 1) ? s_i[5] : s_r;
            unsigned cum = 0;
            unsigned npre = prefix;
            int nrem = rem;
            for (int bin = 255; bin >= 0; --bin) {
                unsigned cc = shist[bin];
                if (cum + cc >= (unsigned)rem) {
                    nrem = rem - (int)cum;
                    npre = prefix | ((unsigned)bin << shift);
                    break;
                }
                cum += cc;
            }
            s_r = nrem; s_prefix = npre;
        }
        __syncthreads();
        prefix = s_prefix;
    }
    const unsigned T = prefix;

    // 7. tie-exact final sum
    double ls = 0.0;
    for (int i = tid; i < cnt; i += SEL_T) {
        unsigned kk = (i < CAP) ? s_cand[i] : sp[i - CAP];
        if (kk > T) ls += (double)key_to_val(kk);
    }
    #pragma unroll
    for (int off = 32; off > 0; off >>= 1) ls += __shfl_down(ls, off);
    __syncthreads();
    if (lane == 0) sredd[wave][0] = ls;
    __syncthreads();

    if (tid == 0) {
        double cs = 0.0;
        for (int w = 0; w < 16; ++w) cs += sredd[w][0];
        double total = s_d[3] + cs + (double)s_r * (double)key_to_val(T);

        const int npos = s_i[0], nlc = s_i[2], hasgt = s_i[6];
        double cls_l = 0.0, bbox_l = 0.0, ldm_l = 0.0;
        if (hasgt && npos > 0) {
            double neg_mean = (keep > 0) ? total / (double)keep : 0.0;
            cls_l = s_d[0] / (double)npos + neg_mean;
            bbox_l = s_d[1] / ((double)npos * 4.0);
        }
        if (hasgt && nlc > 0) {
            ldm_l = s_d[2] / ((double)nlc * 196.0);
        }
        out[b]             = (float)cls_l;
        out[BATCH + b]     = (float)bbox_l;
        out[2 * BATCH + b] = (float)ldm_l;
    }
}

extern "C" void kernel_launch(void* const* d_in, const int* in_sizes, int n_in,
                              void* d_out, int out_size, void* d_ws, size_t ws_size,
                              hipStream_t stream) {
    const float* cls     = (const float*)d_in[0];
    const float* breg    = (const float*)d_in[1];
    const float* lreg    = (const float*)d_in[2];
    const float* anchors = (const float*)d_in[3];
    const float* ann     = (const float*)d_in[4];

    char* ws = (char*)d_ws;
    int4*     pcnt  = (int4*)(ws + OFF_PCNT);
    double*   psum  = (double*)(ws + OFF_PSUM);
    unsigned* histS = (unsigned*)(ws + OFF_HSLOT);
    unsigned* keys  = (unsigned*)(ws + OFF_KEYS);
    unsigned* spill = (unsigned*)(ws + OFF_SPILL);
    float*    out   = (float*)d_out;

    hipMemsetAsync(histS, 0, (size_t)BATCH * NSLOT * 256 * 4, stream);
    hipLaunchKernelGGL(k_main, dim3(BATCH * BLOCKS_PER), dim3(256), 0, stream,
                       cls, breg, lreg, anchors, ann, pcnt, psum, keys, histS);
    hipLaunchKernelGGL(k_sel, dim3(BATCH), dim3(SEL_T), 0, stream,
                       ann, pcnt, psum, histS, keys, spill, out);
}